// Round 2
// baseline (4706.450 us; speedup 1.0000x reference)
//
#include <hip/hip_runtime.h>
#include <math.h>

#define KB 8      // spline bins
#define TT 8      // transforms
#define HH 64     // hidden width
#define PHI_N 23  // 3*K - 1
#define BOUNDF 5.0f

// -log(2.5 - (-1.75)) = -log(4.25)
#define LN_P_OUT (-1.4469189829363254f)
// 0.5*log(2*pi)
#define HALF_LN_2PI 0.91893853320467274f

__device__ __forceinline__ float softplusf(float x) {
    // jax.nn.softplus = max(x,0) + log1p(exp(-|x|))
    return fmaxf(x, 0.f) + log1pf(__expf(-fabsf(x)));
}

// LDS layout (floats)
#define SW1_OFF 0            // 192
#define SB1_OFF 192          // 64
#define SW2_OFF 256          // 4096
#define SB2_OFF 4352         // 64
#define SW3_OFF 4416         // 1472
#define SB3_OFF 5888         // 23
#define SM_TOT  5911

__global__ __launch_bounds__(256, 2) void gyro_main(
    const float* __restrict__ z_in,
    const float* __restrict__ log_age,
    const float* __restrict__ bprp0,
    const float* __restrict__ log_bprp0_err,
    const float* __restrict__ mem_prob,
    const float* __restrict__ W1,   // (T,3,H)
    const float* __restrict__ b1,   // (T,H)
    const float* __restrict__ W2,   // (T,H,H)
    const float* __restrict__ b2,   // (T,H)
    const float* __restrict__ W3,   // (T,H,PHI)
    const float* __restrict__ b3,   // (T,PHI)
    double* __restrict__ partials,
    int B)
{
    __shared__ float smem[SM_TOT];

    const int tid = threadIdx.x;
    const int i = blockIdx.x * blockDim.x + tid;
    const bool active = (i < B);

    // predicated input loads; inactive lanes get benign values
    const float c0 = active ? log_age[i] : 0.f;
    const float c1 = active ? bprp0[i] : 0.f;
    const float c2 = active ? log_bprp0_err[i] : 0.f;
    float z = active ? z_in[i] : 0.f;
    const float pm_raw = active ? mem_prob[i] : 0.5f;

    float logdet = 0.f;

    #pragma unroll 1
    for (int t = 0; t < TT; ++t) {
        // ---- stage this transform's weights into LDS ----
        if (t) __syncthreads();   // previous compute must be done before overwrite
        {
            // W1: 192 floats = 48 float4
            const float4* g = (const float4*)(W1 + t * 3 * HH);
            float4* s = (float4*)(smem + SW1_OFF);
            for (int idx = tid; idx < 48; idx += 256) s[idx] = g[idx];
        }
        {
            const float4* g = (const float4*)(W2 + t * HH * HH);   // 1024 float4
            float4* s = (float4*)(smem + SW2_OFF);
            for (int idx = tid; idx < 1024; idx += 256) s[idx] = g[idx];
        }
        {
            const float4* g = (const float4*)(W3 + t * HH * PHI_N); // 368 float4
            float4* s = (float4*)(smem + SW3_OFF);
            for (int idx = tid; idx < 368; idx += 256) s[idx] = g[idx];
        }
        {
            // b1 (64) + b2 (64) + b3 (23) scalars
            if (tid < 64) smem[SB1_OFF + tid] = b1[t * HH + tid];
            else if (tid < 128) smem[SB2_OFF + (tid - 64)] = b2[t * HH + (tid - 64)];
            else if (tid < 128 + PHI_N) smem[SB3_OFF + (tid - 128)] = b3[t * PHI_N + (tid - 128)];
        }
        __syncthreads();

        // ---- layer 1: h1 = relu(ctx @ W1 + b1) ----
        float h1[HH];
        #pragma unroll
        for (int j = 0; j < HH; ++j) {
            float a = smem[SB1_OFF + j];
            a = fmaf(c0, smem[SW1_OFF + 0 * HH + j], a);
            a = fmaf(c1, smem[SW1_OFF + 1 * HH + j], a);
            a = fmaf(c2, smem[SW1_OFF + 2 * HH + j], a);
            h1[j] = fmaxf(a, 0.f);
        }

        // ---- layers 2+3 fused, blocked by 16 outputs of h2 ----
        float phi[PHI_N];
        #pragma unroll
        for (int j3 = 0; j3 < PHI_N; ++j3) phi[j3] = smem[SB3_OFF + j3];

        #pragma unroll 1
        for (int jo = 0; jo < HH / 16; ++jo) {
            float acc[16];
            #pragma unroll
            for (int jj = 0; jj < 16; ++jj) acc[jj] = smem[SB2_OFF + jo * 16 + jj];

            const float* w2c = smem + SW2_OFF + jo * 16;  // column block base
            #pragma unroll
            for (int k2 = 0; k2 < HH; ++k2) {
                const float hv = h1[k2];
                #pragma unroll
                for (int jj = 0; jj < 16; ++jj)
                    acc[jj] = fmaf(hv, w2c[k2 * HH + jj], acc[jj]);
            }

            const float* w3c = smem + SW3_OFF + jo * 16 * PHI_N;
            #pragma unroll
            for (int jj = 0; jj < 16; ++jj) {
                const float v = fmaxf(acc[jj], 0.f);
                #pragma unroll
                for (int j3 = 0; j3 < PHI_N; ++j3)
                    phi[j3] = fmaf(v, w3c[jj * PHI_N + j3], phi[j3]);
            }
        }

        // ---- RQS spline forward on z ----
        float xk[KB + 1], yk[KB + 1], dv[KB + 1];
        {
            float mx = phi[0];
            #pragma unroll
            for (int k = 1; k < KB; ++k) mx = fmaxf(mx, phi[k]);
            float ev[KB]; float se = 0.f;
            #pragma unroll
            for (int k = 0; k < KB; ++k) { ev[k] = __expf(phi[k] - mx); se += ev[k]; }
            const float inv = 1.f / se;
            xk[0] = -BOUNDF;
            float cs = 0.f;
            #pragma unroll
            for (int k = 0; k < KB; ++k) { cs += ev[k]; xk[k + 1] = BOUNDF * (2.f * cs * inv - 1.f); }
        }
        {
            float mx = phi[KB];
            #pragma unroll
            for (int k = 1; k < KB; ++k) mx = fmaxf(mx, phi[KB + k]);
            float ev[KB]; float se = 0.f;
            #pragma unroll
            for (int k = 0; k < KB; ++k) { ev[k] = __expf(phi[KB + k] - mx); se += ev[k]; }
            const float inv = 1.f / se;
            yk[0] = -BOUNDF;
            float cs = 0.f;
            #pragma unroll
            for (int k = 0; k < KB; ++k) { cs += ev[k]; yk[k + 1] = BOUNDF * (2.f * cs * inv - 1.f); }
        }
        dv[0] = 1.f;
        dv[KB] = 1.f;
        #pragma unroll
        for (int k = 0; k < KB - 1; ++k) dv[k + 1] = softplusf(phi[2 * KB + k]);

        const bool inside = fabsf(z) < BOUNDF;
        const float xc = fminf(fmaxf(z, -BOUNDF), BOUNDF);

        float x0 = xk[0], x1 = xk[1], y0 = yk[0], y1 = yk[1], d0c = dv[0], d1c = dv[1];
        #pragma unroll
        for (int m = 1; m < KB; ++m) {
            const bool c = (xc >= xk[m]);
            x0  = c ? xk[m]     : x0;
            x1  = c ? xk[m + 1] : x1;
            y0  = c ? yk[m]     : y0;
            y1  = c ? yk[m + 1] : y1;
            d0c = c ? dv[m]     : d0c;
            d1c = c ? dv[m + 1] : d1c;
        }

        const float wk  = x1 - x0;
        const float hk  = y1 - y0;
        const float s   = hk / wk;
        const float xi  = (xc - x0) / wk;
        const float xi1 = 1.f - xi;
        const float den = s + (d1c + d0c - 2.f * s) * xi * xi1;
        const float y   = y0 + hk * (s * xi * xi + d0c * xi * xi1) / den;
        const float ld  = 2.f * __logf(s)
                        + __logf(d1c * xi * xi + 2.f * s * xi * xi1 + d0c * xi1 * xi1)
                        - 2.f * __logf(den);

        z = inside ? y : z;
        logdet += inside ? ld : 0.f;
    }

    float lc = 0.f;
    if (active) {
        const float logp = -0.5f * z * z - HALF_LN_2PI + logdet;
        float pm = pm_raw;
        pm = (pm != pm) ? 0.9f : pm;       // NaN -> P_MEM_DEFAULT
        const float nfw = pm * 0.95f;      // p_mem * (1 - P_OUTLIER)
        const float a = __logf(nfw) + logp;
        const float b = __logf(1.f - nfw) + LN_P_OUT;
        const float mx2 = fmaxf(a, b);
        const float mn2 = fminf(a, b);
        lc = mx2 + log1pf(__expf(mn2 - mx2));
    }

    // ---- deterministic block reduction (double) ----
    double acc = (double)lc;
    #pragma unroll
    for (int off = 32; off > 0; off >>= 1) acc += __shfl_down(acc, off, 64);

    __shared__ double sm[4];
    const int lane = tid & 63;
    const int wid  = tid >> 6;
    if (lane == 0) sm[wid] = acc;
    __syncthreads();
    if (tid == 0) {
        partials[blockIdx.x] = sm[0] + sm[1] + sm[2] + sm[3];
    }
}

__global__ __launch_bounds__(256) void gyro_reduce(
    const double* __restrict__ partials, int n, float* __restrict__ out, int B)
{
    double s = 0.0;
    for (int i = threadIdx.x; i < n; i += 256) s += partials[i];
    #pragma unroll
    for (int off = 32; off > 0; off >>= 1) s += __shfl_down(s, off, 64);

    __shared__ double sm[4];
    const int lane = threadIdx.x & 63;
    const int wid  = threadIdx.x >> 6;
    if (lane == 0) sm[wid] = s;
    __syncthreads();
    if (threadIdx.x == 0) {
        const double tot = sm[0] + sm[1] + sm[2] + sm[3];
        out[0] = (float)(-tot / (double)B);
    }
}

extern "C" void kernel_launch(void* const* d_in, const int* in_sizes, int n_in,
                              void* d_out, int out_size, void* d_ws, size_t ws_size,
                              hipStream_t stream) {
    const float* z_in   = (const float*)d_in[0];
    const float* lage   = (const float*)d_in[1];
    const float* bprp   = (const float*)d_in[2];
    const float* lberr  = (const float*)d_in[3];
    const float* memp   = (const float*)d_in[4];
    const float* W1     = (const float*)d_in[5];
    const float* b1     = (const float*)d_in[6];
    const float* W2     = (const float*)d_in[7];
    const float* b2     = (const float*)d_in[8];
    const float* W3     = (const float*)d_in[9];
    const float* b3     = (const float*)d_in[10];

    const int B = in_sizes[1];                 // log_age is (B,)
    const int nblocks = (B + 255) / 256;

    double* partials = (double*)d_ws;

    gyro_main<<<nblocks, 256, 0, stream>>>(z_in, lage, bprp, lberr, memp,
                                           W1, b1, W2, b2, W3, b3,
                                           partials, B);
    gyro_reduce<<<1, 256, 0, stream>>>(partials, nblocks, (float*)d_out, B);
}

// Round 3
// 852.845 us; speedup vs baseline: 5.5185x; 5.5185x over previous
//
#include <hip/hip_runtime.h>
#include <hip/hip_bf16.h>
#include <math.h>

#define KB 8
#define TT 8
#define HH 64
#define PHI_N 23
#define BOUNDF 5.0f
#define LN_P_OUT (-1.4469189829363254f)
#define HALF_LN_2PI 0.91893853320467274f
#define ITERS 2

typedef float f32x4 __attribute__((ext_vector_type(4)));
typedef short short8 __attribute__((ext_vector_type(8)));

__device__ __forceinline__ unsigned short f2bf(float x) {
    __hip_bfloat16 h = __float2bfloat16(x);
    return __builtin_bit_cast(unsigned short, h);
}

__device__ __forceinline__ float softplusf(float x) {
    return fmaxf(x, 0.f) + log1pf(__expf(-fabsf(x)));
}

// ---------------- weight pack kernel ----------------
// Packed bf16 layout per t (8192 ushorts):
//   [0,2048):    L1A  [m:4][lane:64][i:8]  A[row=16m+(l&15)][k=8*(l>>4)+i]
//                k<3 -> W1[t][k][row]; k==3 -> b1[t][row]; else 0
//   [2048,6144): L2A  [kt:2][m:4][lane][i] k=32kt+8g+i -> W2[t][k][row]
//   [6144,8192): L3A  [kt:2][mp:2][lane][i] row=16mp+(l&15)<23 -> W3[t][k][row]
__global__ __launch_bounds__(256) void pack_weights(
    const float* __restrict__ W1, const float* __restrict__ b1,
    const float* __restrict__ W2, const float* __restrict__ W3,
    unsigned short* __restrict__ packed)
{
    int gid = blockIdx.x * 256 + threadIdx.x;   // 0..65535
    int t = gid >> 13;
    int r = gid & 8191;
    float val = 0.f;
    if (r < 2048) {
        int m = r >> 9, l = (r >> 3) & 63, i = r & 7;
        int row = 16 * m + (l & 15);
        int k = 8 * (l >> 4) + i;
        if (k < 3) val = W1[t * 192 + k * 64 + row];
        else if (k == 3) val = b1[t * 64 + row];
    } else if (r < 6144) {
        int q = r - 2048;
        int kt = q >> 11; q &= 2047;
        int m = q >> 9, l = (q >> 3) & 63, i = q & 7;
        int row = 16 * m + (l & 15);
        int k = 32 * kt + 8 * (l >> 4) + i;
        val = W2[t * 4096 + k * 64 + row];
    } else {
        int q = r - 6144;
        int kt = q >> 10; q &= 1023;
        int mp = q >> 9, l = (q >> 3) & 63, i = q & 7;
        int row = 16 * mp + (l & 15);
        int k = 32 * kt + 8 * (l >> 4) + i;
        if (row < 23) val = W3[t * 64 * PHI_N + k * PHI_N + row];
    }
    packed[gid] = f2bf(val);
}

// ---------------- main kernel ----------------
__global__ __launch_bounds__(64, 2) void gyro_main(
    const float* __restrict__ z_in,
    const float* __restrict__ log_age,
    const float* __restrict__ bprp0,
    const float* __restrict__ log_bprp0_err,
    const float* __restrict__ mem_prob,
    const float* __restrict__ b2g,
    const float* __restrict__ b3g,
    const unsigned short* __restrict__ packed,
    float* __restrict__ partials,
    int B)
{
    __shared__ unsigned short tile_s[4096];  // 8 KB bf16 64x64 [samp][feat], XOR-swizzled
    __shared__ float phiT[64 * 25];          // 6.4 KB [samp][phi]

    const int tid = threadIdx.x;             // 0..63, one wave
    const int c = tid & 15, g = tid >> 4;
    const int swz = (c & 7) << 4;            // XOR on byte-addr bits 4-6
    char* tb = (char*)tile_s;

    double accsum = 0.0;

    for (int it = 0; it < ITERS; ++it) {
        const int i = blockIdx.x * (64 * ITERS) + it * 64 + tid;
        const bool active = (i < B);

        const float c0 = active ? log_age[i] : 0.f;
        const float c1 = active ? bprp0[i] : 0.f;
        const float c2 = active ? log_bprp0_err[i] : 0.f;
        float z = active ? z_in[i] : 0.f;
        const float pm_raw = active ? mem_prob[i] : 0.5f;

        // ---- ctx B-fragments: B[k][samp], nonzero only k=0..3 (lanes g==0) ----
        short8 bctx[4];
        #pragma unroll
        for (int n = 0; n < 4; ++n) {
            const int src = 16 * n + c;
            const float v0 = __shfl(c0, src);
            const float v1 = __shfl(c1, src);
            const float v2 = __shfl(c2, src);
            short8 f;
            f[0] = (short)f2bf(v0);
            f[1] = (short)f2bf(v1);
            f[2] = (short)f2bf(v2);
            f[3] = (short)0x3F80;   // bias slot (1.0)
            f[4] = 0; f[5] = 0; f[6] = 0; f[7] = 0;
            short8 zf = {0,0,0,0,0,0,0,0};
            bctx[n] = (g == 0) ? f : zf;
        }

        float logdet = 0.f;

        #pragma unroll 1
        for (int t = 0; t < TT; ++t) {
            const unsigned short* pt = packed + t * 8192;

            // ---- load packed A fragments ----
            short8 a1[4], a2[2][4], a3[2][2];
            #pragma unroll
            for (int m = 0; m < 4; ++m)
                a1[m] = *(const short8*)(pt + m * 512 + tid * 8);
            #pragma unroll
            for (int kt = 0; kt < 2; ++kt)
                #pragma unroll
                for (int m = 0; m < 4; ++m)
                    a2[kt][m] = *(const short8*)(pt + 2048 + kt * 2048 + m * 512 + tid * 8);
            #pragma unroll
            for (int kt = 0; kt < 2; ++kt)
                #pragma unroll
                for (int mp = 0; mp < 2; ++mp)
                    a3[kt][mp] = *(const short8*)(pt + 6144 + kt * 1024 + mp * 512 + tid * 8);

            // ---- L1: h1^T = W1^T ctx^T + b1 (bias folded at k=3) ----
            f32x4 hc[4][4];
            #pragma unroll
            for (int m = 0; m < 4; ++m)
                #pragma unroll
                for (int n = 0; n < 4; ++n) {
                    f32x4 acc = {0.f, 0.f, 0.f, 0.f};
                    hc[m][n] = __builtin_amdgcn_mfma_f32_16x16x32_bf16(a1[m], bctx[n], acc, 0, 0, 0);
                }

            // ---- transition 1: relu -> bf16 -> LDS tile [samp][feat] ----
            __syncthreads();
            #pragma unroll
            for (int m = 0; m < 4; ++m)
                #pragma unroll
                for (int n = 0; n < 4; ++n) {
                    const f32x4 v = hc[m][n];
                    unsigned int lo = (unsigned)f2bf(fmaxf(v[0], 0.f)) | ((unsigned)f2bf(fmaxf(v[1], 0.f)) << 16);
                    unsigned int hi = (unsigned)f2bf(fmaxf(v[2], 0.f)) | ((unsigned)f2bf(fmaxf(v[3], 0.f)) << 16);
                    int off = ((16 * n + c) * 128 + (32 * m + 8 * g)) ^ swz;
                    uint2 q; q.x = lo; q.y = hi;
                    *(uint2*)(tb + off) = q;
                }
            __syncthreads();
            short8 hb[2][4];
            #pragma unroll
            for (int kt = 0; kt < 2; ++kt)
                #pragma unroll
                for (int n = 0; n < 4; ++n) {
                    int roff = ((16 * n + c) * 128 + (16 * g + 64 * kt)) ^ swz;
                    hb[kt][n] = *(const short8*)(tb + roff);
                }

            // ---- L2: h2^T = W2^T relu(h1^T) ----
            f32x4 h2[4][4];
            #pragma unroll
            for (int m = 0; m < 4; ++m)
                #pragma unroll
                for (int n = 0; n < 4; ++n) {
                    f32x4 acc = {0.f, 0.f, 0.f, 0.f};
                    #pragma unroll
                    for (int kt = 0; kt < 2; ++kt)
                        acc = __builtin_amdgcn_mfma_f32_16x16x32_bf16(a2[kt][m], hb[kt][n], acc, 0, 0, 0);
                    h2[m][n] = acc;
                }

            // ---- transition 2: +b2, relu -> bf16 -> LDS ----
            f32x4 b2v[4];
            #pragma unroll
            for (int m = 0; m < 4; ++m)
                b2v[m] = *(const f32x4*)(b2g + t * 64 + 16 * m + 4 * g);

            __syncthreads();
            #pragma unroll
            for (int m = 0; m < 4; ++m)
                #pragma unroll
                for (int n = 0; n < 4; ++n) {
                    const f32x4 v = h2[m][n];
                    unsigned int lo = (unsigned)f2bf(fmaxf(v[0] + b2v[m][0], 0.f)) | ((unsigned)f2bf(fmaxf(v[1] + b2v[m][1], 0.f)) << 16);
                    unsigned int hi = (unsigned)f2bf(fmaxf(v[2] + b2v[m][2], 0.f)) | ((unsigned)f2bf(fmaxf(v[3] + b2v[m][3], 0.f)) << 16);
                    int off = ((16 * n + c) * 128 + (32 * m + 8 * g)) ^ swz;
                    uint2 q; q.x = lo; q.y = hi;
                    *(uint2*)(tb + off) = q;
                }
            __syncthreads();
            short8 pb[2][4];
            #pragma unroll
            for (int kt = 0; kt < 2; ++kt)
                #pragma unroll
                for (int n = 0; n < 4; ++n) {
                    int roff = ((16 * n + c) * 128 + (16 * g + 64 * kt)) ^ swz;
                    pb[kt][n] = *(const short8*)(tb + roff);
                }

            // ---- L3: phi^T = W3^T relu(h2^T) ----
            f32x4 pc[2][4];
            #pragma unroll
            for (int mp = 0; mp < 2; ++mp)
                #pragma unroll
                for (int n = 0; n < 4; ++n) {
                    f32x4 acc = {0.f, 0.f, 0.f, 0.f};
                    #pragma unroll
                    for (int kt = 0; kt < 2; ++kt)
                        acc = __builtin_amdgcn_mfma_f32_16x16x32_bf16(a3[kt][mp], pb[kt][n], acc, 0, 0, 0);
                    pc[mp][n] = acc;
                }

            // ---- +b3, transpose phi via LDS [samp][25] ----
            float b3v[2][4];
            #pragma unroll
            for (int mp = 0; mp < 2; ++mp)
                #pragma unroll
                for (int r = 0; r < 4; ++r) {
                    int row = 16 * mp + 4 * g + r;
                    b3v[mp][r] = (row < PHI_N) ? b3g[t * PHI_N + row] : 0.f;
                }

            __syncthreads();
            #pragma unroll
            for (int mp = 0; mp < 2; ++mp)
                #pragma unroll
                for (int n = 0; n < 4; ++n)
                    #pragma unroll
                    for (int r = 0; r < 4; ++r) {
                        int row = 16 * mp + 4 * g + r;
                        if (row < PHI_N)
                            phiT[(16 * n + c) * 25 + row] = pc[mp][n][r] + b3v[mp][r];
                    }
            __syncthreads();

            float phi[PHI_N];
            #pragma unroll
            for (int j = 0; j < PHI_N; ++j) phi[j] = phiT[tid * 25 + j];

            // ---- RQS spline forward ----
            float xk[KB + 1], yk[KB + 1], dv[KB + 1];
            {
                float mx = phi[0];
                #pragma unroll
                for (int k = 1; k < KB; ++k) mx = fmaxf(mx, phi[k]);
                float ev[KB]; float se = 0.f;
                #pragma unroll
                for (int k = 0; k < KB; ++k) { ev[k] = __expf(phi[k] - mx); se += ev[k]; }
                const float inv = 1.f / se;
                xk[0] = -BOUNDF;
                float cs = 0.f;
                #pragma unroll
                for (int k = 0; k < KB; ++k) { cs += ev[k]; xk[k + 1] = BOUNDF * (2.f * cs * inv - 1.f); }
            }
            {
                float mx = phi[KB];
                #pragma unroll
                for (int k = 1; k < KB; ++k) mx = fmaxf(mx, phi[KB + k]);
                float ev[KB]; float se = 0.f;
                #pragma unroll
                for (int k = 0; k < KB; ++k) { ev[k] = __expf(phi[KB + k] - mx); se += ev[k]; }
                const float inv = 1.f / se;
                yk[0] = -BOUNDF;
                float cs = 0.f;
                #pragma unroll
                for (int k = 0; k < KB; ++k) { cs += ev[k]; yk[k + 1] = BOUNDF * (2.f * cs * inv - 1.f); }
            }
            dv[0] = 1.f; dv[KB] = 1.f;
            #pragma unroll
            for (int k = 0; k < KB - 1; ++k) dv[k + 1] = softplusf(phi[2 * KB + k]);

            const bool inside = fabsf(z) < BOUNDF;
            const float xc = fminf(fmaxf(z, -BOUNDF), BOUNDF);

            float x0 = xk[0], x1 = xk[1], y0 = yk[0], y1 = yk[1], d0c = dv[0], d1c = dv[1];
            #pragma unroll
            for (int m = 1; m < KB; ++m) {
                const bool cc = (xc >= xk[m]);
                x0  = cc ? xk[m]     : x0;
                x1  = cc ? xk[m + 1] : x1;
                y0  = cc ? yk[m]     : y0;
                y1  = cc ? yk[m + 1] : y1;
                d0c = cc ? dv[m]     : d0c;
                d1c = cc ? dv[m + 1] : d1c;
            }

            const float wk  = x1 - x0;
            const float hk  = y1 - y0;
            const float s   = hk / wk;
            const float xi  = (xc - x0) / wk;
            const float xi1 = 1.f - xi;
            const float den = s + (d1c + d0c - 2.f * s) * xi * xi1;
            const float y   = y0 + hk * (s * xi * xi + d0c * xi * xi1) / den;
            const float ld  = 2.f * __logf(s)
                            + __logf(d1c * xi * xi + 2.f * s * xi * xi1 + d0c * xi1 * xi1)
                            - 2.f * __logf(den);

            z = inside ? y : z;
            logdet += inside ? ld : 0.f;
        }

        if (active) {
            const float logp = -0.5f * z * z - HALF_LN_2PI + logdet;
            float pm = pm_raw;
            pm = (pm != pm) ? 0.9f : pm;
            const float nfw = pm * 0.95f;
            const float a = __logf(nfw) + logp;
            const float b = __logf(1.f - nfw) + LN_P_OUT;
            const float mx2 = fmaxf(a, b);
            const float mn2 = fminf(a, b);
            accsum += (double)(mx2 + log1pf(__expf(mn2 - mx2)));
        }
    }

    // ---- within-wave deterministic reduction ----
    double wsum = accsum;
    #pragma unroll
    for (int off = 32; off > 0; off >>= 1) wsum += __shfl_down(wsum, off, 64);
    if (tid == 0) partials[blockIdx.x] = (float)wsum;
}

__global__ __launch_bounds__(256) void gyro_reduce(
    const float* __restrict__ partials, int n, float* __restrict__ out, int B)
{
    double s = 0.0;
    for (int i = threadIdx.x; i < n; i += 256) s += (double)partials[i];
    #pragma unroll
    for (int off = 32; off > 0; off >>= 1) s += __shfl_down(s, off, 64);

    __shared__ double sm[4];
    const int lane = threadIdx.x & 63;
    const int wid  = threadIdx.x >> 6;
    if (lane == 0) sm[wid] = s;
    __syncthreads();
    if (threadIdx.x == 0) {
        const double tot = sm[0] + sm[1] + sm[2] + sm[3];
        out[0] = (float)(-tot / (double)B);
    }
}

extern "C" void kernel_launch(void* const* d_in, const int* in_sizes, int n_in,
                              void* d_out, int out_size, void* d_ws, size_t ws_size,
                              hipStream_t stream) {
    const float* z_in   = (const float*)d_in[0];
    const float* lage   = (const float*)d_in[1];
    const float* bprp   = (const float*)d_in[2];
    const float* lberr  = (const float*)d_in[3];
    const float* memp   = (const float*)d_in[4];
    const float* W1     = (const float*)d_in[5];
    const float* b1     = (const float*)d_in[6];
    const float* W2     = (const float*)d_in[7];
    const float* b2     = (const float*)d_in[8];
    const float* W3     = (const float*)d_in[9];
    const float* b3     = (const float*)d_in[10];

    const int B = in_sizes[1];
    const int nblocks = (B + 64 * ITERS - 1) / (64 * ITERS);

    unsigned short* packed = (unsigned short*)d_ws;                 // 128 KB
    float* partials = (float*)((char*)d_ws + 131072);               // nblocks floats

    pack_weights<<<256, 256, 0, stream>>>(W1, b1, W2, W3, packed);
    gyro_main<<<nblocks, 64, 0, stream>>>(z_in, lage, bprp, lberr, memp,
                                          b2, b3, packed, partials, B);
    gyro_reduce<<<1, 256, 0, stream>>>(partials, nblocks, (float*)d_out, B);
}

// Round 4
// 754.312 us; speedup vs baseline: 6.2394x; 1.1306x over previous
//
#include <hip/hip_runtime.h>
#include <hip/hip_bf16.h>
#include <math.h>

#define KB 8
#define TT 8
#define HH 64
#define PHI_N 23
#define BOUNDF 5.0f
#define LN_P_OUT (-1.4469189829363254f)
#define HALF_LN_2PI 0.91893853320467274f
#define ITERS 2

#define TROW 144          // tile row stride in bytes (16-aligned, bank-spread)
#define PHIS 33           // phiT row stride in floats (odd*32-coprime, 2-way reads)
#define SMEM_BYTES 9216   // max(64*TROW, 64*PHIS*4) = max(9216, 8448)

typedef float f32x4 __attribute__((ext_vector_type(4)));
typedef short short8 __attribute__((ext_vector_type(8)));

__device__ __forceinline__ unsigned short f2bf(float x) {
    __hip_bfloat16 h = __float2bfloat16(x);
    return __builtin_bit_cast(unsigned short, h);
}

__device__ __forceinline__ float softplusf(float x) {
    return fmaxf(x, 0.f) + log1pf(__expf(-fabsf(x)));
}

// ---------------- weight pack kernel ----------------
// Packed bf16 layout per t (8192 ushorts):
//   [0,2048):    L1A  [m:4][lane:64][i:8]  A[row=16m+(l&15)][k=8*(l>>4)+i]
//                k<3 -> W1[t][k][row]; k==3 -> b1[t][row]; else 0
//   [2048,6144): L2A  [kt:2][m:4][lane][i] k=32kt+8g+i -> W2[t][k][row]
//   [6144,8192): L3A  [kt:2][mp:2][lane][i] row=16mp+(l&15)<23 -> W3[t][k][row]
__global__ __launch_bounds__(256) void pack_weights(
    const float* __restrict__ W1, const float* __restrict__ b1,
    const float* __restrict__ W2, const float* __restrict__ W3,
    unsigned short* __restrict__ packed)
{
    int gid = blockIdx.x * 256 + threadIdx.x;   // 0..65535
    int t = gid >> 13;
    int r = gid & 8191;
    float val = 0.f;
    if (r < 2048) {
        int m = r >> 9, l = (r >> 3) & 63, i = r & 7;
        int row = 16 * m + (l & 15);
        int k = 8 * (l >> 4) + i;
        if (k < 3) val = W1[t * 192 + k * 64 + row];
        else if (k == 3) val = b1[t * 64 + row];
    } else if (r < 6144) {
        int q = r - 2048;
        int kt = q >> 11; q &= 2047;
        int m = q >> 9, l = (q >> 3) & 63, i = q & 7;
        int row = 16 * m + (l & 15);
        int k = 32 * kt + 8 * (l >> 4) + i;
        val = W2[t * 4096 + k * 64 + row];
    } else {
        int q = r - 6144;
        int kt = q >> 10; q &= 1023;
        int mp = q >> 9, l = (q >> 3) & 63, i = q & 7;
        int row = 16 * mp + (l & 15);
        int k = 32 * kt + 8 * (l >> 4) + i;
        if (row < 23) val = W3[t * 64 * PHI_N + k * PHI_N + row];
    }
    packed[gid] = f2bf(val);
}

// ---------------- main kernel ----------------
__global__ __launch_bounds__(64, 4) void gyro_main(
    const float* __restrict__ z_in,
    const float* __restrict__ log_age,
    const float* __restrict__ bprp0,
    const float* __restrict__ log_bprp0_err,
    const float* __restrict__ mem_prob,
    const float* __restrict__ b2g,
    const float* __restrict__ b3g,
    const unsigned short* __restrict__ packed,
    float* __restrict__ partials,
    int B)
{
    // unioned LDS: bf16 tile (64 rows x 144 B) OR phiT (64 x 33 f32)
    __shared__ alignas(16) char smem_u[SMEM_BYTES];
    char* tb = smem_u;
    float* phiT = (float*)smem_u;

    const int tid = threadIdx.x;             // 0..63, one wave
    const int c = tid & 15, g = tid >> 4;

    double accsum = 0.0;

    for (int it = 0; it < ITERS; ++it) {
        const int i = blockIdx.x * (64 * ITERS) + it * 64 + tid;
        const bool active = (i < B);

        const float c0 = active ? log_age[i] : 0.f;
        const float c1 = active ? bprp0[i] : 0.f;
        const float c2 = active ? log_bprp0_err[i] : 0.f;
        float z = active ? z_in[i] : 0.f;
        const float pm_raw = active ? mem_prob[i] : 0.5f;

        // ---- ctx B-fragments: B[k][samp], nonzero only k=0..3 (lanes g==0) ----
        short8 bctx[4];
        #pragma unroll
        for (int n = 0; n < 4; ++n) {
            const int src = 16 * n + c;
            const float v0 = __shfl(c0, src);
            const float v1 = __shfl(c1, src);
            const float v2 = __shfl(c2, src);
            short8 f;
            f[0] = (short)f2bf(v0);
            f[1] = (short)f2bf(v1);
            f[2] = (short)f2bf(v2);
            f[3] = (short)0x3F80;   // bias slot (1.0)
            f[4] = 0; f[5] = 0; f[6] = 0; f[7] = 0;
            short8 zf = {0,0,0,0,0,0,0,0};
            bctx[n] = (g == 0) ? f : zf;
        }

        float logdet = 0.f;

        #pragma unroll 1
        for (int t = 0; t < TT; ++t) {
            const unsigned short* pt = packed + t * 8192;

            // ---- load packed A fragments ----
            short8 a1[4], a2[2][4], a3[2][2];
            #pragma unroll
            for (int m = 0; m < 4; ++m)
                a1[m] = *(const short8*)(pt + m * 512 + tid * 8);
            #pragma unroll
            for (int kt = 0; kt < 2; ++kt)
                #pragma unroll
                for (int m = 0; m < 4; ++m)
                    a2[kt][m] = *(const short8*)(pt + 2048 + kt * 2048 + m * 512 + tid * 8);
            #pragma unroll
            for (int kt = 0; kt < 2; ++kt)
                #pragma unroll
                for (int mp = 0; mp < 2; ++mp)
                    a3[kt][mp] = *(const short8*)(pt + 6144 + kt * 1024 + mp * 512 + tid * 8);

            // ---- L1: h1^T = W1^T ctx^T + b1 (bias folded at k=3) ----
            f32x4 hc[4][4];
            #pragma unroll
            for (int m = 0; m < 4; ++m)
                #pragma unroll
                for (int n = 0; n < 4; ++n) {
                    f32x4 acc = {0.f, 0.f, 0.f, 0.f};
                    hc[m][n] = __builtin_amdgcn_mfma_f32_16x16x32_bf16(a1[m], bctx[n], acc, 0, 0, 0);
                }

            // ---- transition 1: relu -> bf16 -> LDS tile [samp][feat] ----
            __syncthreads();   // protects union (phi reads of prev t / prev iter done)
            #pragma unroll
            for (int m = 0; m < 4; ++m)
                #pragma unroll
                for (int n = 0; n < 4; ++n) {
                    const f32x4 v = hc[m][n];
                    unsigned int lo = (unsigned)f2bf(fmaxf(v[0], 0.f)) | ((unsigned)f2bf(fmaxf(v[1], 0.f)) << 16);
                    unsigned int hi = (unsigned)f2bf(fmaxf(v[2], 0.f)) | ((unsigned)f2bf(fmaxf(v[3], 0.f)) << 16);
                    int off = (16 * n + c) * TROW + (32 * m + 8 * g);
                    uint2 q; q.x = lo; q.y = hi;
                    *(uint2*)(tb + off) = q;
                }
            __syncthreads();
            short8 hb[2][4];
            #pragma unroll
            for (int kt = 0; kt < 2; ++kt)
                #pragma unroll
                for (int n = 0; n < 4; ++n) {
                    int roff = (16 * n + c) * TROW + (16 * g + 64 * kt);
                    hb[kt][n] = *(const short8*)(tb + roff);
                }

            // ---- L2: h2^T = W2^T relu(h1^T) ----
            f32x4 h2[4][4];
            #pragma unroll
            for (int m = 0; m < 4; ++m)
                #pragma unroll
                for (int n = 0; n < 4; ++n) {
                    f32x4 acc = {0.f, 0.f, 0.f, 0.f};
                    #pragma unroll
                    for (int kt = 0; kt < 2; ++kt)
                        acc = __builtin_amdgcn_mfma_f32_16x16x32_bf16(a2[kt][m], hb[kt][n], acc, 0, 0, 0);
                    h2[m][n] = acc;
                }

            // ---- transition 2: +b2, relu -> bf16 -> LDS ----
            f32x4 b2v[4];
            #pragma unroll
            for (int m = 0; m < 4; ++m)
                b2v[m] = *(const f32x4*)(b2g + t * 64 + 16 * m + 4 * g);

            __syncthreads();
            #pragma unroll
            for (int m = 0; m < 4; ++m)
                #pragma unroll
                for (int n = 0; n < 4; ++n) {
                    const f32x4 v = h2[m][n];
                    unsigned int lo = (unsigned)f2bf(fmaxf(v[0] + b2v[m][0], 0.f)) | ((unsigned)f2bf(fmaxf(v[1] + b2v[m][1], 0.f)) << 16);
                    unsigned int hi = (unsigned)f2bf(fmaxf(v[2] + b2v[m][2], 0.f)) | ((unsigned)f2bf(fmaxf(v[3] + b2v[m][3], 0.f)) << 16);
                    int off = (16 * n + c) * TROW + (32 * m + 8 * g);
                    uint2 q; q.x = lo; q.y = hi;
                    *(uint2*)(tb + off) = q;
                }
            __syncthreads();
            short8 pb[2][4];
            #pragma unroll
            for (int kt = 0; kt < 2; ++kt)
                #pragma unroll
                for (int n = 0; n < 4; ++n) {
                    int roff = (16 * n + c) * TROW + (16 * g + 64 * kt);
                    pb[kt][n] = *(const short8*)(tb + roff);
                }

            // ---- L3: phi^T = W3^T relu(h2^T) ----
            f32x4 pc[2][4];
            #pragma unroll
            for (int mp = 0; mp < 2; ++mp)
                #pragma unroll
                for (int n = 0; n < 4; ++n) {
                    f32x4 acc = {0.f, 0.f, 0.f, 0.f};
                    #pragma unroll
                    for (int kt = 0; kt < 2; ++kt)
                        acc = __builtin_amdgcn_mfma_f32_16x16x32_bf16(a3[kt][mp], pb[kt][n], acc, 0, 0, 0);
                    pc[mp][n] = acc;
                }

            // ---- +b3, transpose phi via LDS (union with tile; tile dead now) ----
            float b3v[2][4];
            #pragma unroll
            for (int mp = 0; mp < 2; ++mp)
                #pragma unroll
                for (int r = 0; r < 4; ++r) {
                    int row = 16 * mp + 4 * g + r;
                    b3v[mp][r] = (row < PHI_N) ? b3g[t * PHI_N + row] : 0.f;
                }

            __syncthreads();
            #pragma unroll
            for (int mp = 0; mp < 2; ++mp)
                #pragma unroll
                for (int n = 0; n < 4; ++n)
                    #pragma unroll
                    for (int r = 0; r < 4; ++r) {
                        int row = 16 * mp + 4 * g + r;   // <= 31 < PHIS, unconditional
                        phiT[(16 * n + c) * PHIS + row] = pc[mp][n][r] + b3v[mp][r];
                    }
            __syncthreads();

            float phi[PHI_N];
            #pragma unroll
            for (int j = 0; j < PHI_N; ++j) phi[j] = phiT[tid * PHIS + j];

            // ---- RQS spline forward ----
            float xk[KB + 1], yk[KB + 1], dv[KB + 1];
            {
                float mx = phi[0];
                #pragma unroll
                for (int k = 1; k < KB; ++k) mx = fmaxf(mx, phi[k]);
                float ev[KB]; float se = 0.f;
                #pragma unroll
                for (int k = 0; k < KB; ++k) { ev[k] = __expf(phi[k] - mx); se += ev[k]; }
                const float inv = 1.f / se;
                xk[0] = -BOUNDF;
                float cs = 0.f;
                #pragma unroll
                for (int k = 0; k < KB; ++k) { cs += ev[k]; xk[k + 1] = BOUNDF * (2.f * cs * inv - 1.f); }
            }
            {
                float mx = phi[KB];
                #pragma unroll
                for (int k = 1; k < KB; ++k) mx = fmaxf(mx, phi[KB + k]);
                float ev[KB]; float se = 0.f;
                #pragma unroll
                for (int k = 0; k < KB; ++k) { ev[k] = __expf(phi[KB + k] - mx); se += ev[k]; }
                const float inv = 1.f / se;
                yk[0] = -BOUNDF;
                float cs = 0.f;
                #pragma unroll
                for (int k = 0; k < KB; ++k) { cs += ev[k]; yk[k + 1] = BOUNDF * (2.f * cs * inv - 1.f); }
            }
            dv[0] = 1.f; dv[KB] = 1.f;
            #pragma unroll
            for (int k = 0; k < KB - 1; ++k) dv[k + 1] = softplusf(phi[2 * KB + k]);

            const bool inside = fabsf(z) < BOUNDF;
            const float xc = fminf(fmaxf(z, -BOUNDF), BOUNDF);

            float x0 = xk[0], x1 = xk[1], y0 = yk[0], y1 = yk[1], d0c = dv[0], d1c = dv[1];
            #pragma unroll
            for (int m = 1; m < KB; ++m) {
                const bool cc = (xc >= xk[m]);
                x0  = cc ? xk[m]     : x0;
                x1  = cc ? xk[m + 1] : x1;
                y0  = cc ? yk[m]     : y0;
                y1  = cc ? yk[m + 1] : y1;
                d0c = cc ? dv[m]     : d0c;
                d1c = cc ? dv[m + 1] : d1c;
            }

            const float wk  = x1 - x0;
            const float hk  = y1 - y0;
            const float s   = hk / wk;
            const float xi  = (xc - x0) / wk;
            const float xi1 = 1.f - xi;
            const float den = s + (d1c + d0c - 2.f * s) * xi * xi1;
            const float y   = y0 + hk * (s * xi * xi + d0c * xi * xi1) / den;
            const float ld  = 2.f * __logf(s)
                            + __logf(d1c * xi * xi + 2.f * s * xi * xi1 + d0c * xi1 * xi1)
                            - 2.f * __logf(den);

            z = inside ? y : z;
            logdet += inside ? ld : 0.f;
        }

        if (active) {
            const float logp = -0.5f * z * z - HALF_LN_2PI + logdet;
            float pm = pm_raw;
            pm = (pm != pm) ? 0.9f : pm;
            const float nfw = pm * 0.95f;
            const float a = __logf(nfw) + logp;
            const float b = __logf(1.f - nfw) + LN_P_OUT;
            const float mx2 = fmaxf(a, b);
            const float mn2 = fminf(a, b);
            accsum += (double)(mx2 + log1pf(__expf(mn2 - mx2)));
        }
    }

    // ---- within-wave deterministic reduction (single wave: no LDS needed) ----
    double wsum = accsum;
    #pragma unroll
    for (int off = 32; off > 0; off >>= 1) wsum += __shfl_down(wsum, off, 64);
    if (tid == 0) partials[blockIdx.x] = (float)wsum;
}

__global__ __launch_bounds__(256) void gyro_reduce(
    const float* __restrict__ partials, int n, float* __restrict__ out, int B)
{
    double s = 0.0;
    for (int i = threadIdx.x; i < n; i += 256) s += (double)partials[i];
    #pragma unroll
    for (int off = 32; off > 0; off >>= 1) s += __shfl_down(s, off, 64);

    __shared__ double sm[4];
    const int lane = threadIdx.x & 63;
    const int wid  = threadIdx.x >> 6;
    if (lane == 0) sm[wid] = s;
    __syncthreads();
    if (threadIdx.x == 0) {
        const double tot = sm[0] + sm[1] + sm[2] + sm[3];
        out[0] = (float)(-tot / (double)B);
    }
}

extern "C" void kernel_launch(void* const* d_in, const int* in_sizes, int n_in,
                              void* d_out, int out_size, void* d_ws, size_t ws_size,
                              hipStream_t stream) {
    const float* z_in   = (const float*)d_in[0];
    const float* lage   = (const float*)d_in[1];
    const float* bprp   = (const float*)d_in[2];
    const float* lberr  = (const float*)d_in[3];
    const float* memp   = (const float*)d_in[4];
    const float* W1     = (const float*)d_in[5];
    const float* b1     = (const float*)d_in[6];
    const float* W2     = (const float*)d_in[7];
    const float* b2     = (const float*)d_in[8];
    const float* W3     = (const float*)d_in[9];
    const float* b3     = (const float*)d_in[10];

    const int B = in_sizes[1];
    const int nblocks = (B + 64 * ITERS - 1) / (64 * ITERS);

    unsigned short* packed = (unsigned short*)d_ws;                 // 128 KB
    float* partials = (float*)((char*)d_ws + 131072);               // nblocks floats

    pack_weights<<<256, 256, 0, stream>>>(W1, b1, W2, W3, packed);
    gyro_main<<<nblocks, 64, 0, stream>>>(z_in, lage, bprp, lberr, memp,
                                          b2, b3, packed, partials, B);
    gyro_reduce<<<1, 256, 0, stream>>>(partials, nblocks, (float*)d_out, B);
}

// Round 5
// 748.901 us; speedup vs baseline: 6.2845x; 1.0072x over previous
//
#include <hip/hip_runtime.h>
#include <hip/hip_bf16.h>
#include <math.h>

#define KB 8
#define TT 8
#define HH 64
#define PHI_N 23
#define BOUNDF 5.0f
#define LN_P_OUT (-1.4469189829363254f)
#define HALF_LN_2PI 0.91893853320467274f
#define ITERS 2

#define TROW 144          // tile row stride in bytes (16-aligned, bank-spread)
#define PHIS 33           // phiT row stride in floats
#define SMEM_BYTES 9216   // max(64*TROW, 64*PHIS*4)

typedef float f32x4 __attribute__((ext_vector_type(4)));
typedef short short8 __attribute__((ext_vector_type(8)));

__device__ __forceinline__ unsigned short f2bf(float x) {
    __hip_bfloat16 h = __float2bfloat16(x);
    return __builtin_bit_cast(unsigned short, h);
}

__device__ __forceinline__ float softplusf(float x) {
    return fmaxf(x, 0.f) + log1pf(__expf(-fabsf(x)));
}

// ---------------- weight pack kernel ----------------
// Packed bf16 layout per t (8192 ushorts):
//   [0,2048):    L1A  [m:4][lane:64][i:8]  A[row=16m+(l&15)][k=8*(l>>4)+i]
//                k<3 -> W1[t][k][row]; k==3 -> b1[t][row]; else 0
//   [2048,6144): L2A  [kt:2][m:4][lane][i] k=32kt+8g+i -> W2[t][k][row]
//   [6144,8192): L3A  [kt:2][mp:2][lane][i] row=16mp+(l&15)<23 -> W3[t][k][row]
__global__ __launch_bounds__(256) void pack_weights(
    const float* __restrict__ W1, const float* __restrict__ b1,
    const float* __restrict__ W2, const float* __restrict__ W3,
    unsigned short* __restrict__ packed)
{
    int gid = blockIdx.x * 256 + threadIdx.x;   // 0..65535
    int t = gid >> 13;
    int r = gid & 8191;
    float val = 0.f;
    if (r < 2048) {
        int m = r >> 9, l = (r >> 3) & 63, i = r & 7;
        int row = 16 * m + (l & 15);
        int k = 8 * (l >> 4) + i;
        if (k < 3) val = W1[t * 192 + k * 64 + row];
        else if (k == 3) val = b1[t * 64 + row];
    } else if (r < 6144) {
        int q = r - 2048;
        int kt = q >> 11; q &= 2047;
        int m = q >> 9, l = (q >> 3) & 63, i = q & 7;
        int row = 16 * m + (l & 15);
        int k = 32 * kt + 8 * (l >> 4) + i;
        val = W2[t * 4096 + k * 64 + row];
    } else {
        int q = r - 6144;
        int kt = q >> 10; q &= 1023;
        int mp = q >> 9, l = (q >> 3) & 63, i = q & 7;
        int row = 16 * mp + (l & 15);
        int k = 32 * kt + 8 * (l >> 4) + i;
        if (row < 23) val = W3[t * 64 * PHI_N + k * PHI_N + row];
    }
    packed[gid] = f2bf(val);
}

// ---------------- main kernel ----------------
__global__ __launch_bounds__(64, 3) void gyro_main(
    const float* __restrict__ z_in,
    const float* __restrict__ log_age,
    const float* __restrict__ bprp0,
    const float* __restrict__ log_bprp0_err,
    const float* __restrict__ mem_prob,
    const float* __restrict__ b2g,
    const float* __restrict__ b3g,
    const unsigned short* __restrict__ packed,
    float* __restrict__ partials,
    int B)
{
    // unioned LDS: bf16 tile (64 rows x 144 B) OR phiT (64 x 33 f32)
    __shared__ alignas(16) char smem_u[SMEM_BYTES];
    char* tb = smem_u;
    float* phiT = (float*)smem_u;

    const int tid = threadIdx.x;             // 0..63, one wave
    const int c = tid & 15, g = tid >> 4;

    double accsum = 0.0;

    for (int it = 0; it < ITERS; ++it) {
        const int i = blockIdx.x * (64 * ITERS) + it * 64 + tid;
        const bool active = (i < B);

        const float c0 = active ? log_age[i] : 0.f;
        const float c1 = active ? bprp0[i] : 0.f;
        const float c2 = active ? log_bprp0_err[i] : 0.f;
        float z = active ? z_in[i] : 0.f;
        const float pm_raw = active ? mem_prob[i] : 0.5f;

        // ---- ctx B-fragments: B[k][samp], nonzero only k=0..3 (lanes g==0) ----
        short8 bctx[4];
        #pragma unroll
        for (int n = 0; n < 4; ++n) {
            const int src = 16 * n + c;
            const float v0 = __shfl(c0, src);
            const float v1 = __shfl(c1, src);
            const float v2 = __shfl(c2, src);
            short8 f;
            f[0] = (short)f2bf(v0);
            f[1] = (short)f2bf(v1);
            f[2] = (short)f2bf(v2);
            f[3] = (short)0x3F80;   // bias slot (1.0)
            f[4] = 0; f[5] = 0; f[6] = 0; f[7] = 0;
            short8 zf = {0,0,0,0,0,0,0,0};
            bctx[n] = (g == 0) ? f : zf;
        }

        float logdet = 0.f;

        #pragma unroll 1
        for (int t = 0; t < TT; ++t) {
            const unsigned short* pt = packed + t * 8192;

            // ---- L1 + transition1, streamed per m (16 live regs, not 64) ----
            __syncthreads();   // prev phi reads done before tile overwrite
            #pragma unroll
            for (int m = 0; m < 4; ++m) {
                const short8 a1m = *(const short8*)(pt + m * 512 + tid * 8);
                #pragma unroll
                for (int n = 0; n < 4; ++n) {
                    f32x4 acc = {0.f, 0.f, 0.f, 0.f};
                    acc = __builtin_amdgcn_mfma_f32_16x16x32_bf16(a1m, bctx[n], acc, 0, 0, 0);
                    unsigned int lo = (unsigned)f2bf(fmaxf(acc[0], 0.f)) | ((unsigned)f2bf(fmaxf(acc[1], 0.f)) << 16);
                    unsigned int hi = (unsigned)f2bf(fmaxf(acc[2], 0.f)) | ((unsigned)f2bf(fmaxf(acc[3], 0.f)) << 16);
                    int off = (16 * n + c) * TROW + (32 * m + 8 * g);
                    uint2 q; q.x = lo; q.y = hi;
                    *(uint2*)(tb + off) = q;
                }
            }
            __syncthreads();

            short8 hb[2][4];
            #pragma unroll
            for (int kt = 0; kt < 2; ++kt)
                #pragma unroll
                for (int n = 0; n < 4; ++n) {
                    int roff = (16 * n + c) * TROW + (16 * g + 64 * kt);
                    hb[kt][n] = *(const short8*)(tb + roff);
                }
            __syncthreads();   // hb in regs; tile buffer free for reuse

            // ---- L2 + transition2, streamed per m ----
            #pragma unroll
            for (int m = 0; m < 4; ++m) {
                const short8 a2m0 = *(const short8*)(pt + 2048 + m * 512 + tid * 8);
                const short8 a2m1 = *(const short8*)(pt + 4096 + m * 512 + tid * 8);
                const f32x4 b2m = *(const f32x4*)(b2g + t * 64 + 16 * m + 4 * g);
                #pragma unroll
                for (int n = 0; n < 4; ++n) {
                    f32x4 acc = {0.f, 0.f, 0.f, 0.f};
                    acc = __builtin_amdgcn_mfma_f32_16x16x32_bf16(a2m0, hb[0][n], acc, 0, 0, 0);
                    acc = __builtin_amdgcn_mfma_f32_16x16x32_bf16(a2m1, hb[1][n], acc, 0, 0, 0);
                    unsigned int lo = (unsigned)f2bf(fmaxf(acc[0] + b2m[0], 0.f)) | ((unsigned)f2bf(fmaxf(acc[1] + b2m[1], 0.f)) << 16);
                    unsigned int hi = (unsigned)f2bf(fmaxf(acc[2] + b2m[2], 0.f)) | ((unsigned)f2bf(fmaxf(acc[3] + b2m[3], 0.f)) << 16);
                    int off = (16 * n + c) * TROW + (32 * m + 8 * g);
                    uint2 q; q.x = lo; q.y = hi;
                    *(uint2*)(tb + off) = q;
                }
            }
            __syncthreads();

            short8 pb[2][4];
            #pragma unroll
            for (int kt = 0; kt < 2; ++kt)
                #pragma unroll
                for (int n = 0; n < 4; ++n) {
                    int roff = (16 * n + c) * TROW + (16 * g + 64 * kt);
                    pb[kt][n] = *(const short8*)(tb + roff);
                }
            __syncthreads();   // pb in regs; buffer free for phiT

            // ---- L3 + phi transpose, streamed per mp ----
            #pragma unroll
            for (int mp = 0; mp < 2; ++mp) {
                const short8 a3m0 = *(const short8*)(pt + 6144 + mp * 512 + tid * 8);
                const short8 a3m1 = *(const short8*)(pt + 7168 + mp * 512 + tid * 8);
                float b3v[4];
                #pragma unroll
                for (int r = 0; r < 4; ++r) {
                    int row = 16 * mp + 4 * g + r;
                    b3v[r] = (row < PHI_N) ? b3g[t * PHI_N + row] : 0.f;
                }
                #pragma unroll
                for (int n = 0; n < 4; ++n) {
                    f32x4 acc = {0.f, 0.f, 0.f, 0.f};
                    acc = __builtin_amdgcn_mfma_f32_16x16x32_bf16(a3m0, pb[0][n], acc, 0, 0, 0);
                    acc = __builtin_amdgcn_mfma_f32_16x16x32_bf16(a3m1, pb[1][n], acc, 0, 0, 0);
                    #pragma unroll
                    for (int r = 0; r < 4; ++r) {
                        int row = 16 * mp + 4 * g + r;   // <= 31 < PHIS
                        phiT[(16 * n + c) * PHIS + row] = acc[r] + b3v[r];
                    }
                }
            }
            __syncthreads();

            float phi[PHI_N];
            #pragma unroll
            for (int j = 0; j < PHI_N; ++j) phi[j] = phiT[tid * PHIS + j];

            // ---- RQS spline forward ----
            float xk[KB + 1], yk[KB + 1], dv[KB + 1];
            {
                float mx = phi[0];
                #pragma unroll
                for (int k = 1; k < KB; ++k) mx = fmaxf(mx, phi[k]);
                float ev[KB]; float se = 0.f;
                #pragma unroll
                for (int k = 0; k < KB; ++k) { ev[k] = __expf(phi[k] - mx); se += ev[k]; }
                const float inv = 1.f / se;
                xk[0] = -BOUNDF;
                float cs = 0.f;
                #pragma unroll
                for (int k = 0; k < KB; ++k) { cs += ev[k]; xk[k + 1] = BOUNDF * (2.f * cs * inv - 1.f); }
            }
            {
                float mx = phi[KB];
                #pragma unroll
                for (int k = 1; k < KB; ++k) mx = fmaxf(mx, phi[KB + k]);
                float ev[KB]; float se = 0.f;
                #pragma unroll
                for (int k = 0; k < KB; ++k) { ev[k] = __expf(phi[KB + k] - mx); se += ev[k]; }
                const float inv = 1.f / se;
                yk[0] = -BOUNDF;
                float cs = 0.f;
                #pragma unroll
                for (int k = 0; k < KB; ++k) { cs += ev[k]; yk[k + 1] = BOUNDF * (2.f * cs * inv - 1.f); }
            }
            dv[0] = 1.f; dv[KB] = 1.f;
            #pragma unroll
            for (int k = 0; k < KB - 1; ++k) dv[k + 1] = softplusf(phi[2 * KB + k]);

            const bool inside = fabsf(z) < BOUNDF;
            const float xc = fminf(fmaxf(z, -BOUNDF), BOUNDF);

            float x0 = xk[0], x1 = xk[1], y0 = yk[0], y1 = yk[1], d0c = dv[0], d1c = dv[1];
            #pragma unroll
            for (int m = 1; m < KB; ++m) {
                const bool cc = (xc >= xk[m]);
                x0  = cc ? xk[m]     : x0;
                x1  = cc ? xk[m + 1] : x1;
                y0  = cc ? yk[m]     : y0;
                y1  = cc ? yk[m + 1] : y1;
                d0c = cc ? dv[m]     : d0c;
                d1c = cc ? dv[m + 1] : d1c;
            }

            const float wk  = x1 - x0;
            const float hk  = y1 - y0;
            const float s   = hk / wk;
            const float xi  = (xc - x0) / wk;
            const float xi1 = 1.f - xi;
            const float den = s + (d1c + d0c - 2.f * s) * xi * xi1;
            const float y   = y0 + hk * (s * xi * xi + d0c * xi * xi1) / den;
            const float ld  = 2.f * __logf(s)
                            + __logf(d1c * xi * xi + 2.f * s * xi * xi1 + d0c * xi1 * xi1)
                            - 2.f * __logf(den);

            z = inside ? y : z;
            logdet += inside ? ld : 0.f;
        }

        if (active) {
            const float logp = -0.5f * z * z - HALF_LN_2PI + logdet;
            float pm = pm_raw;
            pm = (pm != pm) ? 0.9f : pm;
            const float nfw = pm * 0.95f;
            const float a = __logf(nfw) + logp;
            const float b = __logf(1.f - nfw) + LN_P_OUT;
            const float mx2 = fmaxf(a, b);
            const float mn2 = fminf(a, b);
            accsum += (double)(mx2 + log1pf(__expf(mn2 - mx2)));
        }
    }

    // ---- within-wave deterministic reduction ----
    double wsum = accsum;
    #pragma unroll
    for (int off = 32; off > 0; off >>= 1) wsum += __shfl_down(wsum, off, 64);
    if (tid == 0) partials[blockIdx.x] = (float)wsum;
}

__global__ __launch_bounds__(256) void gyro_reduce(
    const float* __restrict__ partials, int n, float* __restrict__ out, int B)
{
    double s = 0.0;
    for (int i = threadIdx.x; i < n; i += 256) s += (double)partials[i];
    #pragma unroll
    for (int off = 32; off > 0; off >>= 1) s += __shfl_down(s, off, 64);

    __shared__ double sm[4];
    const int lane = threadIdx.x & 63;
    const int wid  = threadIdx.x >> 6;
    if (lane == 0) sm[wid] = s;
    __syncthreads();
    if (threadIdx.x == 0) {
        const double tot = sm[0] + sm[1] + sm[2] + sm[3];
        out[0] = (float)(-tot / (double)B);
    }
}

extern "C" void kernel_launch(void* const* d_in, const int* in_sizes, int n_in,
                              void* d_out, int out_size, void* d_ws, size_t ws_size,
                              hipStream_t stream) {
    const float* z_in   = (const float*)d_in[0];
    const float* lage   = (const float*)d_in[1];
    const float* bprp   = (const float*)d_in[2];
    const float* lberr  = (const float*)d_in[3];
    const float* memp   = (const float*)d_in[4];
    const float* W1     = (const float*)d_in[5];
    const float* b1     = (const float*)d_in[6];
    const float* W2     = (const float*)d_in[7];
    const float* b2     = (const float*)d_in[8];
    const float* W3     = (const float*)d_in[9];
    const float* b3     = (const float*)d_in[10];

    const int B = in_sizes[1];
    const int nblocks = (B + 64 * ITERS - 1) / (64 * ITERS);

    unsigned short* packed = (unsigned short*)d_ws;                 // 128 KB
    float* partials = (float*)((char*)d_ws + 131072);               // nblocks floats

    pack_weights<<<256, 256, 0, stream>>>(W1, b1, W2, W3, packed);
    gyro_main<<<nblocks, 64, 0, stream>>>(z_in, lage, bprp, lberr, memp,
                                          b2, b3, packed, partials, B);
    gyro_reduce<<<1, 256, 0, stream>>>(partials, nblocks, (float*)d_out, B);
}